// Round 1
// baseline (134.049 us; speedup 1.0000x reference)
//
#include <hip/hip_runtime.h>
#include <hip/hip_bf16.h>

#define N_EDGES 1000000
#define N_TILES (N_EDGES / 16)
#define N_NODES 100000

typedef __attribute__((ext_vector_type(8))) short short8;
typedef __attribute__((ext_vector_type(4))) int intx4;
typedef __attribute__((ext_vector_type(4))) float floatx4;

__device__ __forceinline__ short f2bf(float f) {
    __bf16 b = (__bf16)f;           // RNE convert, native on gfx950
    return __builtin_bit_cast(short, b);
}

union BI { short8 s8; intx4 i4; __hip_bfloat162 b2[4]; };

// |a-b| in bf16 (packed): 4x hsub2 + 4x v_and_b32
__device__ __forceinline__ short8 dabs8(short8 a, short8 b) {
    BI ua, ub, ud;
    ua.s8 = a; ub.s8 = b;
#pragma unroll
    for (int i = 0; i < 4; ++i) ud.b2[i] = __hsub2(ua.b2[i], ub.b2[i]);
    ud.i4 &= 0x7fff7fff;            // bf16 abs, packed
    return ud.s8;
}
// a*b in bf16 (packed)
__device__ __forceinline__ short8 pmul8(short8 a, short8 b) {
    BI ua, ub, up;
    ua.s8 = a; ub.s8 = b;
#pragma unroll
    for (int i = 0; i < 4; ++i) up.b2[i] = __hmul2(ua.b2[i], ub.b2[i]);
    return up.s8;
}

// ---- h fp32 -> bf16, 8 elems/thread
__global__ __launch_bounds__(256) void conv_kernel(const float* __restrict__ h,
                                                   unsigned short* __restrict__ hb) {
    const int i = blockIdx.x * blockDim.x + threadIdx.x;
    if (i >= (N_NODES * 64) / 8) return;
    const float* p = h + (long)i * 8;
    floatx4 a = *(const floatx4*)p;
    floatx4 b = *(const floatx4*)(p + 4);
    short8 o;
    o[0] = f2bf(a[0]); o[1] = f2bf(a[1]); o[2] = f2bf(a[2]); o[3] = f2bf(a[3]);
    o[4] = f2bf(b[0]); o[5] = f2bf(b[1]); o[6] = f2bf(b[2]); o[7] = f2bf(b[3]);
    *(short8*)(hb + (long)i * 8) = o;
}

// ---- W prep: one block per output n (32 blocks x 256 threads)
__global__ __launch_bounds__(256) void wprep_kernel(const float* __restrict__ gamma,
                                                    const float* __restrict__ beta,
                                                    const float* __restrict__ W1,
                                                    unsigned short* __restrict__ Wt,
                                                    float* __restrict__ GB) {
    const int n = blockIdx.x;
    const int k = threadIdx.x;
    const float w1 = W1[k * 32 + n];
    float G = gamma[k] * w1;
    float B = beta[k] * w1;
    Wt[n * 256 + k] = (unsigned short)f2bf(G);
    G += __shfl_xor(G, 1);  B += __shfl_xor(B, 1);
    G += __shfl_xor(G, 2);  B += __shfl_xor(B, 2);
    G += __shfl_xor(G, 4);  B += __shfl_xor(B, 4);
    G += __shfl_xor(G, 8);  B += __shfl_xor(B, 8);
    G += __shfl_xor(G, 16); B += __shfl_xor(B, 16);
    G += __shfl_xor(G, 32); B += __shfl_xor(B, 32);
    __shared__ float sG[4], sB[4];
    if ((k & 63) == 0) { sG[k >> 6] = G; sB[k >> 6] = B; }
    __syncthreads();
    if (k == 0) {
        GB[n]      = sG[0] + sG[1] + sG[2] + sG[3];
        GB[32 + n] = sB[0] + sB[1] + sB[2] + sB[3];
    }
}

// ---- main: R8 configuration.
// 16 edges/wave; MFMA computes MLP, LN stats (ones-B + Gram diag), and the
// final W2 dot (selector-B). B-fragments in LDS (fragment-major, stride 33).
// NEW vs R7: 3-slot register pipeline — row gathers issued 2 tiles ahead
// (index chain 3 deep), mod-3 unroll rotates slots with zero register
// copies. Targets the gather-latency stall (SIMD issue was only ~29%).
__global__ __launch_bounds__(256) void edgehead_kernel(
    const unsigned short* __restrict__ hb,
    const int* __restrict__ ep,
    const float* __restrict__ b1,
    const float* __restrict__ W2,
    const float* __restrict__ b2p,
    const unsigned short* __restrict__ Wt,
    const float* __restrict__ GB,
    float* __restrict__ out)
{
    const int lane = threadIdx.x & 63;
    const int c = lane & 15;   // A-row index; D column
    const int q = lane >> 4;   // quad
    const int wid = (int)((blockIdx.x * blockDim.x + threadIdx.x) >> 6);
    const int nw = (int)((gridDim.x * blockDim.x) >> 6);

    // Stage Wt into LDS, fragment-major: row r = n (0..31), chunk j = 4s+q (0..31).
    __shared__ short lds_wt[32 * 33 * 8];   // 16,896 B
    for (int idx = threadIdx.x; idx < 1024; idx += 256) {
        const int r = idx >> 5, j = idx & 31;
        *(short8*)(lds_wt + (r * 33 + j) * 8) = *(const short8*)(Wt + r * 256 + 8 * j);
    }
    __syncthreads();

    // per-lane base offset (in shorts) for its fragments: row c / row 16+c, chunk q
    int wt_off = (c * 33 + q) * 8;          // nt=0; nt=1 adds 16*33*8
    short8 ones;
#pragma unroll
    for (int j = 0; j < 8; ++j) ones[j] = (short)0x3F80;   // bf16 1.0

    // selector B for the final dot: B[8q+j][c] = (c == 4q+(j&3)) ? 1 : 0
    short8 wsel;
#pragma unroll
    for (int j = 0; j < 8; ++j) wsel[j] = (c == 4 * q + (j & 3)) ? (short)0x3F80 : (short)0;

    const float Gn0 = GB[c],      Gn1 = GB[16 + c];
    const float Bn0 = GB[32 + c] + b1[c];
    const float Bn1 = GB[48 + c] + b1[16 + c];
    const float W20 = W2[c],      W21 = W2[16 + c];
    const float b2  = b2p[0];

    int t = wid;
    if (t >= N_TILES) return;

    // indices for a tile (clamped: out-of-range tiles read wave's own base tile;
    // their rows are loaded but never consumed for a store)
#define IDX_LOAD(tt, S, D) { int _t = (tt); if (_t >= N_TILES) _t = wid;          \
                             const int _e = _t * 16 + c;                          \
                             S = ep[_e]; D = ep[N_EDGES + _e]; }
#define ROW_ISSUE(S, D, U0, U1, V0, V1)                                           \
    U0 = *(const short8*)(hb + (long)(S) * 64 + 8 * q);                           \
    U1 = *(const short8*)(hb + (long)(S) * 64 + 8 * q + 32);                      \
    V0 = *(const short8*)(hb + (long)(D) * 64 + 8 * q);                           \
    V1 = *(const short8*)(hb + (long)(D) * 64 + 8 * q + 32);

    short8 aU0, aU1, aV0, aV1;   // slot A (tiles j%3==0)
    short8 bU0, bU1, bV0, bV1;   // slot B (tiles j%3==1)
    short8 cU0, cU1, cV0, cV1;   // slot C (tiles j%3==2)
    int sA, dA, sB, dB, sC, dC;

    // ---- prologue: fill 2 slots, indices 3 tiles deep
    IDX_LOAD(t,          sA, dA);
    IDX_LOAD(t + nw,     sB, dB);
    IDX_LOAD(t + 2 * nw, sC, dC);
    ROW_ISSUE(sA, dA, aU0, aU1, aV0, aV1);      // tile j=0
    ROW_ISSUE(sB, dB, bU0, bU1, bV0, bV1);      // tile j=1
    IDX_LOAD(t + 3 * nw, sA, dA);               // slot A next issues tile 3
    IDX_LOAD(t + 4 * nw, sB, dB);               // slot B next issues tile 4

    // body for tile t: issue rows(t+2nw) into NXT slot, reload its idx (t+5nw),
    // compute from CUR slot, store, advance.
#define BODY(U0, U1, V0, V1, NU0, NU1, NV0, NV1, SN, DN)                          \
  {                                                                               \
    if (t >= N_TILES) goto tail;                                                  \
    asm("" : "+v"(wt_off));  /* defeat LICM: re-read B-fragments from LDS */      \
    ROW_ISSUE(SN, DN, NU0, NU1, NV0, NV1);                                        \
    IDX_LOAD(t + 5 * nw, SN, DN);                                                 \
    floatx4 acc0 = {0.f, 0.f, 0.f, 0.f};                                          \
    floatx4 acc1 = {0.f, 0.f, 0.f, 0.f};                                          \
    floatx4 asum = {0.f, 0.f, 0.f, 0.f};   /* row sums */                         \
    floatx4 agrm = {0.f, 0.f, 0.f, 0.f};   /* Gram; diag = sum of squares */      \
    _Pragma("unroll")                                                             \
    for (int s = 0; s < 8; ++s) {                                                 \
      short8 af;                                                                  \
      switch (s) {                                                                \
        case 0: af = U0; break;                                                   \
        case 1: af = U1; break;                                                   \
        case 2: af = V0; break;                                                   \
        case 3: af = V1; break;                                                   \
        case 4: af = dabs8(U0, V0); break;    /* lazy: short live ranges */       \
        case 5: af = dabs8(U1, V1); break;                                        \
        case 6: af = pmul8(U0, V0); break;                                        \
        default: af = pmul8(U1, V1); break;                                       \
      }                                                                           \
      const short8 bf0 = *(const short8*)(lds_wt + wt_off + s * 32);              \
      const short8 bf1 = *(const short8*)(lds_wt + wt_off + 16 * 33 * 8 + s * 32);\
      acc0 = __builtin_amdgcn_mfma_f32_16x16x32_bf16(af, bf0,  acc0, 0, 0, 0);    \
      acc1 = __builtin_amdgcn_mfma_f32_16x16x32_bf16(af, bf1,  acc1, 0, 0, 0);    \
      asum = __builtin_amdgcn_mfma_f32_16x16x32_bf16(af, ones, asum, 0, 0, 0);    \
      agrm = __builtin_amdgcn_mfma_f32_16x16x32_bf16(af, af,   agrm, 0, 0, 0);    \
    }                                                                             \
    float ss[4];                                                                  \
    _Pragma("unroll")                                                             \
    for (int r = 0; r < 4; ++r) ss[r] = __shfl(agrm[r], 20 * q + r);              \
    short8 af2;                                                                   \
    _Pragma("unroll")                                                             \
    for (int r = 0; r < 4; ++r) {                                                 \
      const float mu  = asum[r] * (1.f / 256.f);                                  \
      const float var = fmaf(ss[r], 1.f / 256.f, -mu * mu);                       \
      const float rs  = rsqrtf(var + 1e-5f);                                      \
      float h0 = fmaf(rs, fmaf(-mu, Gn0, acc0[r]), Bn0); h0 = fmaxf(h0, 0.f);     \
      float h1 = fmaf(rs, fmaf(-mu, Gn1, acc1[r]), Bn1); h1 = fmaxf(h1, 0.f);     \
      af2[r]     = f2bf(h0 * W20);                                                \
      af2[4 + r] = f2bf(h1 * W21);                                                \
    }                                                                             \
    floatx4 dfin = {0.f, 0.f, 0.f, 0.f};                                          \
    dfin = __builtin_amdgcn_mfma_f32_16x16x32_bf16(af2, wsel, dfin, 0, 0, 0);     \
    float part = (dfin[0] + dfin[1]) + (dfin[2] + dfin[3]);                       \
    part += __shfl_xor(part, 16);                                                 \
    part += __shfl_xor(part, 32);                                                 \
    if (q == 0) out[t * 16 + c] = part + b2;   /* coalesced 64B store */          \
    t += nw;                                                                      \
  }

    for (;;) {
        // tile j%3==0: compute A, issue C (tile j+2), reload C idx (tile j+5)
        BODY(aU0, aU1, aV0, aV1, cU0, cU1, cV0, cV1, sC, dC);
        // tile j%3==1: compute B, issue A
        BODY(bU0, bU1, bV0, bV1, aU0, aU1, aV0, aV1, sA, dA);
        // tile j%3==2: compute C, issue B
        BODY(cU0, cU1, cV0, cV1, bU0, bU1, bV0, bV1, sB, dB);
    }
tail:
    return;
#undef BODY
#undef ROW_ISSUE
#undef IDX_LOAD
}

extern "C" void kernel_launch(void* const* d_in, const int* in_sizes, int n_in,
                              void* d_out, int out_size, void* d_ws, size_t ws_size,
                              hipStream_t stream) {
    const float* h     = (const float*)d_in[0];
    const int*   ep    = (const int*)d_in[1];
    const float* gamma = (const float*)d_in[2];
    const float* beta  = (const float*)d_in[3];
    const float* W1    = (const float*)d_in[4];
    const float* b1    = (const float*)d_in[5];
    const float* W2    = (const float*)d_in[6];
    const float* b2    = (const float*)d_in[7];
    float* out = (float*)d_out;

    unsigned short* hb = (unsigned short*)d_ws;                      // 12,800,000 B
    unsigned short* Wt = (unsigned short*)((char*)d_ws + 12800000);  // 16,384 B
    float* GB = (float*)((char*)d_ws + 12800000 + 16384);            // 64 floats

    conv_kernel<<<(N_NODES * 64 / 8 + 255) / 256, 256, 0, stream>>>(h, hb);
    wprep_kernel<<<32, 256, 0, stream>>>(gamma, beta, W1, Wt, GB);
    edgehead_kernel<<<2048, 256, 0, stream>>>(hb, ep, b1, W2, b2, Wt, GB, out);
}

// Round 2
// 132.049 us; speedup vs baseline: 1.0152x; 1.0152x over previous
//
#include <hip/hip_runtime.h>
#include <hip/hip_bf16.h>

#define N_EDGES 1000000
#define N_TILES (N_EDGES / 16)
#define N_NODES 100000
#define CONV_BLOCKS ((N_NODES * 64 / 8) / 256)   // 3125, exact

typedef __attribute__((ext_vector_type(8))) short short8;
typedef __attribute__((ext_vector_type(4))) int intx4;
typedef __attribute__((ext_vector_type(4))) float floatx4;

__device__ __forceinline__ short f2bf(float f) {
    __bf16 b = (__bf16)f;           // RNE convert, native on gfx950
    return __builtin_bit_cast(short, b);
}

union BI { short8 s8; intx4 i4; __hip_bfloat162 b2[4]; };

// |a-b| in bf16 (packed): 4x v_pk sub + 4x dword AND (was 8 short-lane ops in R7)
__device__ __forceinline__ short8 dabs8(short8 a, short8 b) {
    BI ua, ub, ud;
    ua.s8 = a; ub.s8 = b;
#pragma unroll
    for (int i = 0; i < 4; ++i) ud.b2[i] = __hsub2(ua.b2[i], ub.b2[i]);
    ud.i4 &= 0x7fff7fff;            // bf16 abs, packed per-dword
    return ud.s8;
}
// a*b in bf16 (packed)
__device__ __forceinline__ short8 pmul8(short8 a, short8 b) {
    BI ua, ub, up;
    ua.s8 = a; ub.s8 = b;
#pragma unroll
    for (int i = 0; i < 4; ++i) up.b2[i] = __hmul2(ua.b2[i], ub.b2[i]);
    return up.s8;
}

// ---- fused prep: blocks [0, 3125) = h fp32->bf16; blocks [3125, 3157) = W prep.
// Saves one kernel launch + gap vs separate wprep.
__global__ __launch_bounds__(256) void prep_kernel(
    const float* __restrict__ h, unsigned short* __restrict__ hb,
    const float* __restrict__ gamma, const float* __restrict__ beta,
    const float* __restrict__ W1, unsigned short* __restrict__ Wt,
    float* __restrict__ GB)
{
    if (blockIdx.x < CONV_BLOCKS) {
        const int i = blockIdx.x * blockDim.x + threadIdx.x;   // < 800000 exactly
        const float* p = h + (long)i * 8;
        floatx4 a = *(const floatx4*)p;
        floatx4 b = *(const floatx4*)(p + 4);
        short8 o;
        o[0] = f2bf(a[0]); o[1] = f2bf(a[1]); o[2] = f2bf(a[2]); o[3] = f2bf(a[3]);
        o[4] = f2bf(b[0]); o[5] = f2bf(b[1]); o[6] = f2bf(b[2]); o[7] = f2bf(b[3]);
        *(short8*)(hb + (long)i * 8) = o;
        return;
    }
    // ---- W prep: one block per output n (32 blocks x 256 threads)
    const int n = blockIdx.x - CONV_BLOCKS;
    const int k = threadIdx.x;
    const float w1 = W1[k * 32 + n];
    float G = gamma[k] * w1;
    float B = beta[k] * w1;
    Wt[n * 256 + k] = (unsigned short)f2bf(G);
    G += __shfl_xor(G, 1);  B += __shfl_xor(B, 1);
    G += __shfl_xor(G, 2);  B += __shfl_xor(B, 2);
    G += __shfl_xor(G, 4);  B += __shfl_xor(B, 4);
    G += __shfl_xor(G, 8);  B += __shfl_xor(B, 8);
    G += __shfl_xor(G, 16); B += __shfl_xor(B, 16);
    G += __shfl_xor(G, 32); B += __shfl_xor(B, 32);
    __shared__ float sG[4], sB[4];
    if ((k & 63) == 0) { sG[k >> 6] = G; sB[k >> 6] = B; }
    __syncthreads();
    if (k == 0) {
        GB[n]      = sG[0] + sG[1] + sG[2] + sG[3];
        GB[32 + n] = sB[0] + sB[1] + sB[2] + sB[3];
    }
}

// ---- main: R9 configuration.
// R7 structure (1-deep prefetch, 56-VGPR class, max 8 waves/SIMD) but mod-2
// unrolled ping-pong slots: the 16 per-tile v_mov slot copies of R7 are gone,
// bf16-abs is packed (dword AND), feat fragments built lazily in the MFMA
// switch. Pure issue-work reduction at constant occupancy / memory behavior.
__global__ __launch_bounds__(256) void edgehead_kernel(
    const unsigned short* __restrict__ hb,
    const int* __restrict__ ep,
    const float* __restrict__ b1,
    const float* __restrict__ W2,
    const float* __restrict__ b2p,
    const unsigned short* __restrict__ Wt,
    const float* __restrict__ GB,
    float* __restrict__ out)
{
    const int lane = threadIdx.x & 63;
    const int c = lane & 15;   // A-row index; D column
    const int q = lane >> 4;   // quad
    const int wid = (int)((blockIdx.x * blockDim.x + threadIdx.x) >> 6);
    const int nw = (int)((gridDim.x * blockDim.x) >> 6);

    // Stage Wt into LDS, fragment-major: row r = n (0..31), chunk j = 4s+q (0..31).
    __shared__ short lds_wt[32 * 33 * 8];   // 16,896 B
    for (int idx = threadIdx.x; idx < 1024; idx += 256) {
        const int r = idx >> 5, j = idx & 31;
        *(short8*)(lds_wt + (r * 33 + j) * 8) = *(const short8*)(Wt + r * 256 + 8 * j);
    }
    __syncthreads();

    // per-lane base offset (in shorts) for its fragments: row c / row 16+c, chunk q
    int wt_off = (c * 33 + q) * 8;          // nt=0; nt=1 adds 16*33*8
    short8 ones;
#pragma unroll
    for (int j = 0; j < 8; ++j) ones[j] = (short)0x3F80;   // bf16 1.0

    // selector B for the final dot: B[8q+j][c] = (c == 4q+(j&3)) ? 1 : 0
    short8 wsel;
#pragma unroll
    for (int j = 0; j < 8; ++j) wsel[j] = (c == 4 * q + (j & 3)) ? (short)0x3F80 : (short)0;

    const float Gn0 = GB[c],      Gn1 = GB[16 + c];
    const float Bn0 = GB[32 + c] + b1[c];
    const float Bn1 = GB[48 + c] + b1[16 + c];
    const float W20 = W2[c],      W21 = W2[16 + c];
    const float b2  = b2p[0];

    int t = wid;
    if (t >= N_TILES) return;

    // indices for a tile (clamped: out-of-range tiles read wave's own base tile;
    // their rows are loaded but never consumed for a store)
#define IDX_LOAD(tt, S, D) { int _t = (tt); if (_t >= N_TILES) _t = wid;          \
                             const int _e = _t * 16 + c;                          \
                             S = ep[_e]; D = ep[N_EDGES + _e]; }
#define ROW_ISSUE(S, D, U0, U1, V0, V1)                                           \
    U0 = *(const short8*)(hb + (long)(S) * 64 + 8 * q);                           \
    U1 = *(const short8*)(hb + (long)(S) * 64 + 8 * q + 32);                      \
    V0 = *(const short8*)(hb + (long)(D) * 64 + 8 * q);                           \
    V1 = *(const short8*)(hb + (long)(D) * 64 + 8 * q + 32);

    short8 aU0, aU1, aV0, aV1;   // slot A (even bodies)
    short8 bU0, bU1, bV0, bV1;   // slot B (odd bodies)
    int sA, dA, sB, dB;

    // ---- prologue: rows(t) into A; idx(t+nw) in B-regs; idx(t+2nw) in A-regs
    IDX_LOAD(t, sA, dA);
    ROW_ISSUE(sA, dA, aU0, aU1, aV0, aV1);
    IDX_LOAD(t + nw,     sB, dB);
    IDX_LOAD(t + 2 * nw, sA, dA);

    // body for tile t (computing slot CUR): issue rows(t+nw) from (SN,DN) into
    // slot NXT, then refill (SN,DN) <- idx(t+3nw) (next consumed 2 bodies later).
#define BODY(U0, U1, V0, V1, NU0, NU1, NV0, NV1, SN, DN)                          \
  {                                                                               \
    if (t >= N_TILES) goto tail;                                                  \
    asm("" : "+v"(wt_off));  /* defeat LICM: re-read B-fragments from LDS */      \
    ROW_ISSUE(SN, DN, NU0, NU1, NV0, NV1);                                        \
    IDX_LOAD(t + 3 * nw, SN, DN);                                                 \
    floatx4 acc0 = {0.f, 0.f, 0.f, 0.f};                                          \
    floatx4 acc1 = {0.f, 0.f, 0.f, 0.f};                                          \
    floatx4 asum = {0.f, 0.f, 0.f, 0.f};   /* row sums */                         \
    floatx4 agrm = {0.f, 0.f, 0.f, 0.f};   /* Gram; diag = sum of squares */      \
    _Pragma("unroll")                                                             \
    for (int s = 0; s < 8; ++s) {                                                 \
      short8 af;                                                                  \
      switch (s) {                                                                \
        case 0: af = U0; break;                                                   \
        case 1: af = U1; break;                                                   \
        case 2: af = V0; break;                                                   \
        case 3: af = V1; break;                                                   \
        case 4: af = dabs8(U0, V0); break;    /* lazy: short live ranges */       \
        case 5: af = dabs8(U1, V1); break;                                        \
        case 6: af = pmul8(U0, V0); break;                                        \
        default: af = pmul8(U1, V1); break;                                       \
      }                                                                           \
      const short8 bf0 = *(const short8*)(lds_wt + wt_off + s * 32);              \
      const short8 bf1 = *(const short8*)(lds_wt + wt_off + 16 * 33 * 8 + s * 32);\
      acc0 = __builtin_amdgcn_mfma_f32_16x16x32_bf16(af, bf0,  acc0, 0, 0, 0);    \
      acc1 = __builtin_amdgcn_mfma_f32_16x16x32_bf16(af, bf1,  acc1, 0, 0, 0);    \
      asum = __builtin_amdgcn_mfma_f32_16x16x32_bf16(af, ones, asum, 0, 0, 0);    \
      agrm = __builtin_amdgcn_mfma_f32_16x16x32_bf16(af, af,   agrm, 0, 0, 0);    \
    }                                                                             \
    float ss[4];                                                                  \
    _Pragma("unroll")                                                             \
    for (int r = 0; r < 4; ++r) ss[r] = __shfl(agrm[r], 20 * q + r);              \
    short8 af2;                                                                   \
    _Pragma("unroll")                                                             \
    for (int r = 0; r < 4; ++r) {                                                 \
      const float mu  = asum[r] * (1.f / 256.f);                                  \
      const float var = fmaf(ss[r], 1.f / 256.f, -mu * mu);                       \
      const float rs  = rsqrtf(var + 1e-5f);                                      \
      float h0 = fmaf(rs, fmaf(-mu, Gn0, acc0[r]), Bn0); h0 = fmaxf(h0, 0.f);     \
      float h1 = fmaf(rs, fmaf(-mu, Gn1, acc1[r]), Bn1); h1 = fmaxf(h1, 0.f);     \
      af2[r]     = f2bf(h0 * W20);                                                \
      af2[4 + r] = f2bf(h1 * W21);                                                \
    }                                                                             \
    floatx4 dfin = {0.f, 0.f, 0.f, 0.f};                                          \
    dfin = __builtin_amdgcn_mfma_f32_16x16x32_bf16(af2, wsel, dfin, 0, 0, 0);     \
    float part = (dfin[0] + dfin[1]) + (dfin[2] + dfin[3]);                       \
    part += __shfl_xor(part, 16);                                                 \
    part += __shfl_xor(part, 32);                                                 \
    if (q == 0) out[t * 16 + c] = part + b2;   /* coalesced 64B store */          \
    t += nw;                                                                      \
  }

    for (;;) {
        // even body: compute A(t), issue B rows (t+nw), refill B idx (t+3nw)
        BODY(aU0, aU1, aV0, aV1, bU0, bU1, bV0, bV1, sB, dB);
        // odd body: compute B, issue A, refill A idx
        BODY(bU0, bU1, bV0, bV1, aU0, aU1, aV0, aV1, sA, dA);
    }
tail:
    return;
#undef BODY
#undef ROW_ISSUE
#undef IDX_LOAD
}

extern "C" void kernel_launch(void* const* d_in, const int* in_sizes, int n_in,
                              void* d_out, int out_size, void* d_ws, size_t ws_size,
                              hipStream_t stream) {
    const float* h     = (const float*)d_in[0];
    const int*   ep    = (const int*)d_in[1];
    const float* gamma = (const float*)d_in[2];
    const float* beta  = (const float*)d_in[3];
    const float* W1    = (const float*)d_in[4];
    const float* b1    = (const float*)d_in[5];
    const float* W2    = (const float*)d_in[6];
    const float* b2    = (const float*)d_in[7];
    float* out = (float*)d_out;

    unsigned short* hb = (unsigned short*)d_ws;                      // 12,800,000 B
    unsigned short* Wt = (unsigned short*)((char*)d_ws + 12800000);  // 16,384 B
    float* GB = (float*)((char*)d_ws + 12800000 + 16384);            // 64 floats

    prep_kernel<<<CONV_BLOCKS + 32, 256, 0, stream>>>(h, hb, gamma, beta, W1, Wt, GB);
    edgehead_kernel<<<2048, 256, 0, stream>>>(hb, ep, b1, W2, b2, Wt, GB, out);
}